// Round 7
// baseline (1998.911 us; speedup 1.0000x reference)
//
#include <hip/hip_runtime.h>

#define N_NODES 100000
#define N_EDGES 1600000
#define N_GRAPHS 64
#define HDIM 150
#define PASSES 4
#define MROWS_PAD 100032   // 1563 * 64
#define SCAN_NBLK 391      // ceil(100000/256)
#define PLANE 20480        // LDS bytes per A-plane: 64 rows x 320B

typedef __attribute__((ext_vector_type(8))) short bf16x8;
typedef __attribute__((ext_vector_type(4))) float f32x4;

__device__ __forceinline__ ushort bf16_rne(float x) {
  uint u = __float_as_uint(x);
  u += 0x7FFFu + ((u >> 16) & 1u);
  return (ushort)(u >> 16);
}
__device__ __forceinline__ float bf16f(ushort h) { return __uint_as_float(((uint)h) << 16); }

// ---------------- CSR build ----------------
__global__ void hist_kernel(const int* __restrict__ dst, int* __restrict__ counts, int n) {
  int i = blockIdx.x * blockDim.x + threadIdx.x;
  if (i < n) atomicAdd(&counts[dst[i]], 1);
}

__global__ __launch_bounds__(256) void scan1_kernel(const int* __restrict__ counts,
                                                    int* __restrict__ partials) {
  int i = blockIdx.x * 256 + threadIdx.x;
  int v = (i < N_NODES) ? counts[i] : 0;
#pragma unroll
  for (int o = 32; o; o >>= 1) v += __shfl_down(v, o);
  __shared__ int ws4[4];
  if ((threadIdx.x & 63) == 0) ws4[threadIdx.x >> 6] = v;
  __syncthreads();
  if (threadIdx.x == 0) partials[blockIdx.x] = ws4[0] + ws4[1] + ws4[2] + ws4[3];
}

__global__ __launch_bounds__(512) void scan2_kernel(int* __restrict__ partials,
                                                    int* __restrict__ row_start) {
  __shared__ int s[512];
  int t = threadIdx.x;
  int v = (t < SCAN_NBLK) ? partials[t] : 0;
  s[t] = v;
  __syncthreads();
  for (int o = 1; o < 512; o <<= 1) {
    int u = (t >= o) ? s[t - o] : 0;
    __syncthreads();
    s[t] += u;
    __syncthreads();
  }
  if (t < SCAN_NBLK) partials[t] = s[t] - v;
  if (t == 0) row_start[N_NODES] = s[511];
}

__global__ __launch_bounds__(256) void scan3_kernel(const int* __restrict__ counts,
    const int* __restrict__ partials, int* __restrict__ row_start, int* __restrict__ cursor) {
  __shared__ int s[256];
  int t = threadIdx.x, i = blockIdx.x * 256 + t;
  int v = (i < N_NODES) ? counts[i] : 0;
  s[t] = v;
  __syncthreads();
  for (int o = 1; o < 256; o <<= 1) {
    int u = (t >= o) ? s[t - o] : 0;
    __syncthreads();
    s[t] += u;
    __syncthreads();
  }
  if (i < N_NODES) {
    int ex = s[t] - v + partials[blockIdx.x];
    row_start[i] = ex; cursor[i] = ex;
  }
}

__global__ void fill_kernel(const int* __restrict__ src, const int* __restrict__ dst,
                            int* __restrict__ cursor, int* __restrict__ csr_src, int n) {
  int i = blockIdx.x * blockDim.x + threadIdx.x;
  if (i < n) {
    int pos = atomicAdd(&cursor[dst[i]], 1);
    csr_src[pos] = src[i];
  }
}

// ---------------- weight split: Wcat[ch*160+dd][k], 960x160, bf16 hi/lo ----------------
__global__ void wbuild_kernel(const float* __restrict__ wih, const float* __restrict__ whh,
                              ushort* __restrict__ Whi, ushort* __restrict__ Wlo) {
  int idx = blockIdx.x * 256 + threadIdx.x;
  if (idx >= 960 * 160) return;
  int n = idx / 160, k = idx - n * 160;
  int ch = n / 160, dd = n - ch * 160;
  float v = 0.f;
  if (dd < HDIM && k < HDIM)
    v = (ch < 3) ? wih[(ch * HDIM + dd) * HDIM + k] : whh[((ch - 3) * HDIM + dd) * HDIM + k];
  ushort hi = bf16_rne(v);
  ushort lo = bf16_rne(v - bf16f(hi));
  Whi[idx] = hi; Wlo[idx] = lo;
}

// ---------------- segment sum (round-5 proven form): fp32 gather -> X hi/lo ----------------
__global__ __launch_bounds__(256) void segsum_kernel(const float* __restrict__ h, const int hstride,
    const int* __restrict__ row_start, const int* __restrict__ csr_src,
    ushort* __restrict__ Xhi, ushort* __restrict__ Xlo) {
  int node = blockIdx.x * 4 + (threadIdx.x >> 6);
  if (node >= N_NODES) return;
  int lane = threadIdx.x & 63;
  int b = row_start[node], e = row_start[node + 1];
  int cnt = e - b;
  float a0 = 0.f, a1 = 0.f, a2 = 0.f;
  const bool l22 = lane < 22;

  for (int base = 0; base < cnt; base += 64) {
    const int nb = min(64, cnt - base);
    int myidx = (base + lane < cnt) ? csr_src[b + base + lane] : 0;
    int jj = 0;
    for (; jj + 4 <= nb; jj += 4) {
      const int s0 = __shfl(myidx, jj);
      const int s1 = __shfl(myidx, jj + 1);
      const int s2 = __shfl(myidx, jj + 2);
      const int s3 = __shfl(myidx, jj + 3);
      const float* r0 = h + (size_t)s0 * hstride;
      const float* r1 = h + (size_t)s1 * hstride;
      const float* r2 = h + (size_t)s2 * hstride;
      const float* r3 = h + (size_t)s3 * hstride;
      float v00 = r0[lane],      v10 = r1[lane],      v20 = r2[lane],      v30 = r3[lane];
      float v01 = r0[lane + 64], v11 = r1[lane + 64], v21 = r2[lane + 64], v31 = r3[lane + 64];
      float v02 = 0.f, v12 = 0.f, v22 = 0.f, v32 = 0.f;
      if (l22) {
        v02 = r0[lane + 128]; v12 = r1[lane + 128];
        v22 = r2[lane + 128]; v32 = r3[lane + 128];
      }
      a0 += (v00 + v10) + (v20 + v30);
      a1 += (v01 + v11) + (v21 + v31);
      a2 += (v02 + v12) + (v22 + v32);
    }
    for (; jj < nb; ++jj) {
      const int s0 = __shfl(myidx, jj);
      const float* r0 = h + (size_t)s0 * hstride;
      a0 += r0[lane];
      a1 += r0[lane + 64];
      if (l22) a2 += r0[lane + 128];
    }
  }

  int basep = node * 160;
  ushort h0 = bf16_rne(a0), l0 = bf16_rne(a0 - bf16f(h0));
  ushort h1 = bf16_rne(a1), l1 = bf16_rne(a1 - bf16f(h1));
  Xhi[basep + lane] = h0; Xlo[basep + lane] = l0;
  Xhi[basep + 64 + lane] = h1; Xlo[basep + 64 + lane] = l1;
  if (lane < 32) {
    ushort h2 = 0, l2 = 0;
    if (l22) { h2 = bf16_rne(a2); l2 = bf16_rne(a2 - bf16f(h2)); }
    Xhi[basep + 128 + lane] = h2; Xlo[basep + 128 + lane] = l2;
  }
}

// ---------------- fused MFMA GRU, single-stage full-K ----------------
// LDS: 4 planes (Xhi,Xlo,Hhi,Hlo) x 64 rows x 160 cols (XOR-octet swizzled).
// Stage everything ONCE (waves 0/1 stage X planes; waves 2/3 split fp32 H rows
// into hi/lo in-register), ONE barrier, then a straight-line barrier-free
// region: 40 ds_read_b128 + 30 B-loads + 180 MFMA per wave. Epilogue as before.
__global__ __launch_bounds__(256, 2) void gru_mfma_kernel(
    const ushort* __restrict__ Xhi, const ushort* __restrict__ Xlo,
    const float* __restrict__ hcur, const int hstride,
    const ushort* __restrict__ Whi, const ushort* __restrict__ Wlo,
    const float* __restrict__ bih, const float* __restrict__ bhh,
    float* __restrict__ hnext) {
  __shared__ __align__(16) char smem[4 * PLANE];  // 80KB; first 24KB reused in epilogue
  // XCD-aware swizzle (5 dblk of one mblk consecutive on the same XCD)
  const int flat = blockIdx.x;
  const int xcd = flat & 7;
  const int q = flat >> 3;           // 0..979
  const int dblk = q % 5;
  const int mblk = (q / 5) * 8 + xcd;
  if (mblk >= 1563) return;

  const int tid = threadIdx.x;
  const int w = tid >> 6;
  const int l = tid & 63;
  const int c16 = l & 15;
  const int koct = l >> 4;

  // ---- one-time staging ----
  if (w < 2) {
    // X plane w: 1280 chunks of 16B, coalesced (k-fastest)
    const ushort* srcp = w ? Xlo : Xhi;
#pragma unroll
    for (int it = 0; it < 20; ++it) {
      int flatc = it * 64 + l;
      int row = flatc / 20, o = flatc - row * 20;
      bf16x8 v = *(const bf16x8*)(srcp + (size_t)(mblk * 64 + row) * 160 + o * 8);
      int osw = (o & ~3) | ((o & 3) ^ ((row >> 1) & 3));
      *(bf16x8*)(smem + w * PLANE + row * 320 + osw * 16) = v;
    }
  } else {
    // H rows [(w-2)*32, +32): fp32 -> split -> planes 2 (hi) and 3 (lo)
    const int rbase = (w - 2) * 32;
#pragma unroll
    for (int it = 0; it < 20; ++it) {
      int flatc = it * 64 + l;
      int row = rbase + flatc / 40;
      int c4 = flatc - (flatc / 40) * 40;
      int gm = mblk * 64 + row;
      float x0 = 0.f, x1 = 0.f, x2 = 0.f, x3 = 0.f;
      if (gm < N_NODES) {
        const float* p = hcur + (size_t)gm * hstride + c4 * 4;
        if (hstride != HDIM || c4 < 37) {
          float4 v4 = *(const float4*)p; x0 = v4.x; x1 = v4.y; x2 = v4.z; x3 = v4.w;
        } else if (c4 == 37) {
          float2 v2 = *(const float2*)p; x0 = v2.x; x1 = v2.y;
        }
      }
      ushort h0 = bf16_rne(x0), h1 = bf16_rne(x1), h2 = bf16_rne(x2), h3 = bf16_rne(x3);
      ushort q0 = bf16_rne(x0 - bf16f(h0)), q1 = bf16_rne(x1 - bf16f(h1));
      ushort q2 = bf16_rne(x2 - bf16f(h2)), q3 = bf16_rne(x3 - bf16f(h3));
      int o = c4 >> 1;
      int osw = (o & ~3) | ((o & 3) ^ ((row >> 1) & 3));
      int boff = row * 320 + osw * 16 + (c4 & 1) * 8;
      ushort4 hv; hv.x = h0; hv.y = h1; hv.z = h2; hv.w = h3;
      ushort4 lv; lv.x = q0; lv.y = q1; lv.z = q2; lv.w = q3;
      *(ushort4*)(smem + 2 * PLANE + boff) = hv;
      *(ushort4*)(smem + 3 * PLANE + boff) = lv;
    }
  }
  __syncthreads();

  // ---- barrier-free K region ----
  const int hi_b = (w < 2) ? 0 : 2;
  const int dt = w & 1;
  const int ch0 = (w < 2) ? 0 : 3;
  const int nbase = dblk * 32 + dt * 16 + c16;

  f32x4 acc[3][4];
#pragma unroll
  for (int a = 0; a < 3; ++a)
#pragma unroll
    for (int b = 0; b < 4; ++b) acc[a][b] = (f32x4){0.f, 0.f, 0.f, 0.f};

#pragma unroll
  for (int kc = 0; kc < 5; ++kc) {
    bf16x8 ahi[4], alo[4];
#pragma unroll
    for (int mt = 0; mt < 4; ++mt) {
      const int r = mt * 16 + c16;
      const int o = kc * 4 + (koct ^ ((r >> 1) & 3));
      ahi[mt] = *(const bf16x8*)(smem + hi_b * PLANE + r * 320 + o * 16);
      alo[mt] = *(const bf16x8*)(smem + (hi_b + 1) * PLANE + r * 320 + o * 16);
    }
    bf16x8 bhi[3], blo[3];
#pragma unroll
    for (int cl = 0; cl < 3; ++cl) {
      const int wo = ((ch0 + cl) * 160 + nbase) * 160 + kc * 32 + koct * 8;
      bhi[cl] = *(const bf16x8*)(Whi + wo);
      blo[cl] = *(const bf16x8*)(Wlo + wo);
    }
#pragma unroll
    for (int cl = 0; cl < 3; ++cl)
#pragma unroll
      for (int mt = 0; mt < 4; ++mt)
        acc[cl][mt] = __builtin_amdgcn_mfma_f32_16x16x32_bf16(ahi[mt], bhi[cl], acc[cl][mt], 0, 0, 0);
#pragma unroll
    for (int cl = 0; cl < 3; ++cl)
#pragma unroll
      for (int mt = 0; mt < 4; ++mt)
        acc[cl][mt] = __builtin_amdgcn_mfma_f32_16x16x32_bf16(ahi[mt], blo[cl], acc[cl][mt], 0, 0, 0);
#pragma unroll
    for (int cl = 0; cl < 3; ++cl)
#pragma unroll
      for (int mt = 0; mt < 4; ++mt)
        acc[cl][mt] = __builtin_amdgcn_mfma_f32_16x16x32_bf16(alo[mt], bhi[cl], acc[cl][mt], 0, 0, 0);
  }
  __syncthreads();

  // ---- epilogue: H-waves publish via LDS; X-waves combine + write hnext ----
  float* eps = (float*)smem;
  if (w >= 2) {
    const int wi = w - 2;
#pragma unroll
    for (int cl = 0; cl < 3; ++cl)
#pragma unroll
      for (int mt = 0; mt < 4; ++mt)
        *(f32x4*)&eps[(((wi * 3 + cl) * 4 + mt) * 64 + l) * 4] = acc[cl][mt];
  }
  __syncthreads();
  if (w < 2) {
    const int d = dblk * 32 + dt * 16 + c16;
    if (d < HDIM) {
      const float bir = bih[d], biz = bih[HDIM + d], bin = bih[2 * HDIM + d];
      const float bhr = bhh[d], bhz = bhh[HDIM + d], bhn = bhh[2 * HDIM + d];
#pragma unroll
      for (int mt = 0; mt < 4; ++mt) {
        const int mb = mblk * 64 + mt * 16 + koct * 4;
        f32x4 hr4 = *(const f32x4*)&eps[(((dt * 3 + 0) * 4 + mt) * 64 + l) * 4];
        f32x4 hz4 = *(const f32x4*)&eps[(((dt * 3 + 1) * 4 + mt) * 64 + l) * 4];
        f32x4 hn4 = *(const f32x4*)&eps[(((dt * 3 + 2) * 4 + mt) * 64 + l) * 4];
#pragma unroll
        for (int j = 0; j < 4; ++j) {
          const int m = mb + j;
          if (m < N_NODES) {
            const float r = 1.f / (1.f + __expf(-(acc[0][mt][j] + bir + hr4[j] + bhr)));
            const float z = 1.f / (1.f + __expf(-(acc[1][mt][j] + biz + hz4[j] + bhz)));
            const float na = acc[2][mt][j] + bin + r * (hn4[j] + bhn);
            const float nn = 1.f - 2.f / (__expf(2.f * na) + 1.f);  // tanh
            const float ho = hcur[(size_t)m * hstride + d];
            hnext[m * 160 + d] = (1.f - z) * nn + z * ho;
          }
        }
      }
    }
  }
}

// ---------------- readout ----------------
__global__ __launch_bounds__(64) void graph_accum_kernel(const float* __restrict__ h,
    const int* __restrict__ gids, float* __restrict__ gacc) {
  const int lane = threadIdx.x;
  const int nb = gridDim.x;
  int chunk = (N_NODES + nb - 1) / nb;
  int b = blockIdx.x * chunk, e = min(b + chunk, N_NODES);
  if (b >= e) return;
  float a0 = 0.f, a1 = 0.f, a2 = 0.f;
  int cur = gids[b];
  for (int i = b; i < e; ++i) {
    int gid = gids[i];
    if (gid != cur) {
      atomicAdd(&gacc[cur * HDIM + lane], a0);
      atomicAdd(&gacc[cur * HDIM + lane + 64], a1);
      if (lane < 22) atomicAdd(&gacc[cur * HDIM + lane + 128], a2);
      a0 = a1 = a2 = 0.f; cur = gid;
    }
    const float* hr = h + (size_t)i * 160;
    a0 += hr[lane]; a1 += hr[lane + 64];
    if (lane < 22) a2 += hr[lane + 128];
  }
  atomicAdd(&gacc[cur * HDIM + lane], a0);
  atomicAdd(&gacc[cur * HDIM + lane + 64], a1);
  if (lane < 22) atomicAdd(&gacc[cur * HDIM + lane + 128], a2);
}

__global__ __launch_bounds__(192) void readout_kernel(const float* __restrict__ gacc,
    const float* __restrict__ fc1w, const float* __restrict__ fc1b,
    const float* __restrict__ fc2w, const float* __restrict__ fc2b,
    const float* __restrict__ fclw, const float* __restrict__ fclb,
    float* __restrict__ out) {
  __shared__ float x0[HDIM];
  __shared__ float y1[80];
  __shared__ float y2[80];
  int g = blockIdx.x, t = threadIdx.x;
  if (t < HDIM) {
    float v = logf(gacc[g * HDIM + t]);
    if (v != v) v = 0.f;
    x0[t] = fmaxf(v, 0.f);
  }
  __syncthreads();
  if (t < 80) {
    float s = fc1b[t];
    for (int k = 0; k < HDIM; ++k) s += x0[k] * fc1w[t * HDIM + k];
    y1[t] = (s > 0.f) ? s : 0.01f * s;
  }
  __syncthreads();
  if (t < 80) {
    float s = fc2b[t];
    for (int k = 0; k < 80; ++k) s += y1[k] * fc2w[t * 80 + k];
    y2[t] = (s > 0.f) ? s : 0.01f * s;
  }
  __syncthreads();
  if (t < 10) {
    float s = fclb[t];
    for (int k = 0; k < 80; ++k) s += y2[k] * fclw[t * 80 + k];
    out[g * 10 + t] = s;
  }
}

// ---------------- launch ----------------
extern "C" void kernel_launch(void* const* d_in, const int* in_sizes, int n_in,
                              void* d_out, int out_size, void* d_ws, size_t ws_size,
                              hipStream_t stream) {
  const float* nodes = (const float*)d_in[0];
  const int* src = (const int*)d_in[1];
  const int* dst = (const int*)d_in[2];
  const int* gids = (const int*)d_in[3];
  const float* wih = (const float*)d_in[4];
  const float* whh = (const float*)d_in[5];
  const float* bih = (const float*)d_in[6];
  const float* bhh = (const float*)d_in[7];
  const float* fc1w = (const float*)d_in[8];
  const float* fc1b = (const float*)d_in[9];
  const float* fc2w = (const float*)d_in[10];
  const float* fc2b = (const float*)d_in[11];
  const float* fclw = (const float*)d_in[12];
  const float* fclb = (const float*)d_in[13];
  float* out = (float*)d_out;

  char* wsp = (char*)d_ws;
  size_t off = 0;
  auto carve = [&](size_t bytes) {
    void* p = wsp + off;
    off += (bytes + 255) & ~(size_t)255;
    return p;
  };
  int* counts   = (int*)carve((size_t)N_NODES * 4);
  int* rowstart = (int*)carve((size_t)(N_NODES + 1) * 4);
  int* cursor   = (int*)carve((size_t)N_NODES * 4);
  int* partials = (int*)carve((size_t)512 * 4);
  int* csr      = (int*)carve((size_t)N_EDGES * 4);
  ushort* Xhi   = (ushort*)carve((size_t)MROWS_PAD * 160 * 2);
  ushort* Xlo   = (ushort*)carve((size_t)MROWS_PAD * 160 * 2);
  float* hA     = (float*)carve((size_t)MROWS_PAD * 160 * 4);
  float* hB     = (float*)carve((size_t)MROWS_PAD * 160 * 4);
  ushort* Whi   = (ushort*)carve((size_t)960 * 160 * 2);
  ushort* Wlo   = (ushort*)carve((size_t)960 * 160 * 2);
  float* gacc   = (float*)carve((size_t)N_GRAPHS * HDIM * 4);
  (void)ws_size; (void)in_sizes; (void)n_in; (void)out_size;

  hipMemsetAsync(counts, 0, (size_t)N_NODES * 4, stream);
  hipMemsetAsync(gacc, 0, (size_t)N_GRAPHS * HDIM * 4, stream);

  hist_kernel<<<(N_EDGES + 255) / 256, 256, 0, stream>>>(dst, counts, N_EDGES);
  scan1_kernel<<<SCAN_NBLK, 256, 0, stream>>>(counts, partials);
  scan2_kernel<<<1, 512, 0, stream>>>(partials, rowstart);
  scan3_kernel<<<SCAN_NBLK, 256, 0, stream>>>(counts, partials, rowstart, cursor);
  fill_kernel<<<(N_EDGES + 255) / 256, 256, 0, stream>>>(src, dst, cursor, csr, N_EDGES);
  wbuild_kernel<<<600, 256, 0, stream>>>(wih, whh, Whi, Wlo);

  const float* hcur = nodes;
  int hstride = HDIM;
  float* hnxt = hA;
  for (int p = 0; p < PASSES; ++p) {
    segsum_kernel<<<25000, 256, 0, stream>>>(hcur, hstride, rowstart, csr, Xhi, Xlo);
    gru_mfma_kernel<<<7840, 256, 0, stream>>>(
        Xhi, Xlo, hcur, hstride, Whi, Wlo, bih, bhh, hnxt);
    hcur = hnxt;
    hstride = 160;
    hnxt = (hnxt == hA) ? hB : hA;
  }
  // final h in hcur (stride 160)

  graph_accum_kernel<<<512, 64, 0, stream>>>(hcur, gids, gacc);
  readout_kernel<<<N_GRAPHS, 192, 0, stream>>>(gacc, fc1w, fc1b, fc2w, fc2b, fclw, fclb, out);
}

// Round 9
// 1603.059 us; speedup vs baseline: 1.2469x; 1.2469x over previous
//
#include <hip/hip_runtime.h>

#define N_NODES 100000
#define N_EDGES 1600000
#define N_GRAPHS 64
#define HDIM 150
#define PASSES 4
#define MROWS_PAD 100032   // 1563 * 64
#define SCAN_NBLK 391      // ceil(100000/256)

typedef __attribute__((ext_vector_type(8))) short bf16x8;
typedef __attribute__((ext_vector_type(4))) float f32x4;

__device__ __forceinline__ ushort bf16_rne(float x) {
  uint u = __float_as_uint(x);
  u += 0x7FFFu + ((u >> 16) & 1u);
  return (ushort)(u >> 16);
}
__device__ __forceinline__ float bf16f(ushort h) { return __uint_as_float(((uint)h) << 16); }

// ---------------- CSR build ----------------
__global__ void hist_kernel(const int* __restrict__ dst, int* __restrict__ counts, int n) {
  int i = blockIdx.x * blockDim.x + threadIdx.x;
  if (i < n) atomicAdd(&counts[dst[i]], 1);
}

__global__ __launch_bounds__(256) void scan1_kernel(const int* __restrict__ counts,
                                                    int* __restrict__ partials) {
  int i = blockIdx.x * 256 + threadIdx.x;
  int v = (i < N_NODES) ? counts[i] : 0;
#pragma unroll
  for (int o = 32; o; o >>= 1) v += __shfl_down(v, o);
  __shared__ int ws4[4];
  if ((threadIdx.x & 63) == 0) ws4[threadIdx.x >> 6] = v;
  __syncthreads();
  if (threadIdx.x == 0) partials[blockIdx.x] = ws4[0] + ws4[1] + ws4[2] + ws4[3];
}

__global__ __launch_bounds__(512) void scan2_kernel(int* __restrict__ partials,
                                                    int* __restrict__ row_start) {
  __shared__ int s[512];
  int t = threadIdx.x;
  int v = (t < SCAN_NBLK) ? partials[t] : 0;
  s[t] = v;
  __syncthreads();
  for (int o = 1; o < 512; o <<= 1) {
    int u = (t >= o) ? s[t - o] : 0;
    __syncthreads();
    s[t] += u;
    __syncthreads();
  }
  if (t < SCAN_NBLK) partials[t] = s[t] - v;
  if (t == 0) row_start[N_NODES] = s[511];
}

__global__ __launch_bounds__(256) void scan3_kernel(const int* __restrict__ counts,
    const int* __restrict__ partials, int* __restrict__ row_start, int* __restrict__ cursor) {
  __shared__ int s[256];
  int t = threadIdx.x, i = blockIdx.x * 256 + t;
  int v = (i < N_NODES) ? counts[i] : 0;
  s[t] = v;
  __syncthreads();
  for (int o = 1; o < 256; o <<= 1) {
    int u = (t >= o) ? s[t - o] : 0;
    __syncthreads();
    s[t] += u;
    __syncthreads();
  }
  if (i < N_NODES) {
    int ex = s[t] - v + partials[blockIdx.x];
    row_start[i] = ex; cursor[i] = ex;
  }
}

__global__ void fill_kernel(const int* __restrict__ src, const int* __restrict__ dst,
                            int* __restrict__ cursor, int* __restrict__ csr_src, int n) {
  int i = blockIdx.x * blockDim.x + threadIdx.x;
  if (i < n) {
    int pos = atomicAdd(&cursor[dst[i]], 1);
    csr_src[pos] = src[i];
  }
}

// ---------------- weight build: transposed coalesced layout ----------------
// Wt[ch][dblk][dt][kc][koct][c16][e]: a wave's B-fragment (cl,kc) = contiguous
// 1KB; per-lane offset = l*8 elements. dd = dblk*32+dt*16+c16, k = kc*32+koct*8+e.
__global__ void wbuild_kernel(const float* __restrict__ wih, const float* __restrict__ whh,
                              ushort* __restrict__ Whi, ushort* __restrict__ Wlo) {
  int idx = blockIdx.x * 256 + threadIdx.x;
  if (idx >= 153600) return;
  int low = idx & 511;
  int e = low & 7, c16 = (low >> 3) & 15, koct = low >> 7;
  int hi = idx >> 9;
  int kc = hi % 5; hi /= 5;
  int dt = hi & 1; hi >>= 1;
  int dblk = hi % 5;
  int ch = hi / 5;
  int dd = dblk * 32 + dt * 16 + c16;
  int k = kc * 32 + koct * 8 + e;
  float v = 0.f;
  if (dd < HDIM && k < HDIM)
    v = (ch < 3) ? wih[(ch * HDIM + dd) * HDIM + k] : whh[((ch - 3) * HDIM + dd) * HDIM + k];
  ushort h = bf16_rne(v);
  ushort l = bf16_rne(v - bf16f(h));
  Whi[idx] = h; Wlo[idx] = l;
}

// ---------------- segment sum (proven round-5 form): fp32 gather -> X hi/lo ----------------
__global__ __launch_bounds__(256) void segsum_kernel(const float* __restrict__ h, const int hstride,
    const int* __restrict__ row_start, const int* __restrict__ csr_src,
    ushort* __restrict__ Xhi, ushort* __restrict__ Xlo) {
  int node = blockIdx.x * 4 + (threadIdx.x >> 6);
  if (node >= N_NODES) return;
  int lane = threadIdx.x & 63;
  int b = row_start[node], e = row_start[node + 1];
  int cnt = e - b;
  float a0 = 0.f, a1 = 0.f, a2 = 0.f;
  const bool l22 = lane < 22;

  for (int base = 0; base < cnt; base += 64) {
    const int nb = min(64, cnt - base);
    int myidx = (base + lane < cnt) ? csr_src[b + base + lane] : 0;
    int jj = 0;
    for (; jj + 4 <= nb; jj += 4) {
      const int s0 = __shfl(myidx, jj);
      const int s1 = __shfl(myidx, jj + 1);
      const int s2 = __shfl(myidx, jj + 2);
      const int s3 = __shfl(myidx, jj + 3);
      const float* r0 = h + (size_t)s0 * hstride;
      const float* r1 = h + (size_t)s1 * hstride;
      const float* r2 = h + (size_t)s2 * hstride;
      const float* r3 = h + (size_t)s3 * hstride;
      float v00 = r0[lane],      v10 = r1[lane],      v20 = r2[lane],      v30 = r3[lane];
      float v01 = r0[lane + 64], v11 = r1[lane + 64], v21 = r2[lane + 64], v31 = r3[lane + 64];
      float v02 = 0.f, v12 = 0.f, v22 = 0.f, v32 = 0.f;
      if (l22) {
        v02 = r0[lane + 128]; v12 = r1[lane + 128];
        v22 = r2[lane + 128]; v32 = r3[lane + 128];
      }
      a0 += (v00 + v10) + (v20 + v30);
      a1 += (v01 + v11) + (v21 + v31);
      a2 += (v02 + v12) + (v22 + v32);
    }
    for (; jj < nb; ++jj) {
      const int s0 = __shfl(myidx, jj);
      const float* r0 = h + (size_t)s0 * hstride;
      a0 += r0[lane];
      a1 += r0[lane + 64];
      if (l22) a2 += r0[lane + 128];
    }
  }

  int basep = node * 160;
  ushort h0 = bf16_rne(a0), l0 = bf16_rne(a0 - bf16f(h0));
  ushort h1 = bf16_rne(a1), l1 = bf16_rne(a1 - bf16f(h1));
  Xhi[basep + lane] = h0; Xlo[basep + lane] = l0;
  Xhi[basep + 64 + lane] = h1; Xlo[basep + 64 + lane] = l1;
  if (lane < 32) {
    ushort h2 = 0, l2 = 0;
    if (l22) { h2 = bf16_rne(a2); l2 = bf16_rne(a2 - bf16f(h2)); }
    Xhi[basep + 128 + lane] = h2; Xlo[basep + 128 + lane] = l2;
  }
}

// ---------------- fused MFMA GRU (round-5 pipeline + coalesced/prefetched B) ----------------
__global__ __launch_bounds__(256) void gru_mfma_kernel(
    const ushort* __restrict__ Xhi, const ushort* __restrict__ Xlo,
    const float* __restrict__ hcur, const int hstride,
    const ushort* __restrict__ Whi, const ushort* __restrict__ Wlo,
    const float* __restrict__ bih, const float* __restrict__ bhh,
    float* __restrict__ hnext) {
  __shared__ ushort smem[2][8192];  // 2 x 16KB k-buffers; f32 scratch in epilogue
  // XCD-aware swizzle (5 dblk of one mblk consecutive on the same XCD)
  const int flat = blockIdx.x;
  const int xcd = flat & 7;
  const int q = flat >> 3;           // 0..979
  const int dblk = q % 5;
  const int mblk = (q / 5) * 8 + xcd;
  if (mblk >= 1563) return;

  const int tid = threadIdx.x;
  const int w = tid >> 6;
  const int l = tid & 63;
  const int c16 = l & 15;
  const int koct = l >> 4;

  // staging map: thread -> (row sr, octet so); swizzled octet sop
  const int sr = tid >> 2;
  const int so = tid & 3;
  const int sop = so ^ ((sr >> 1) & 3);
  const int gm = mblk * 64 + sr;
  const bool rowok = gm < N_NODES;
  const int g_off = gm * 160 + so * 8;
  const int lds_w_off = sr * 64 + sop * 16;  // bytes; + arr*4096 + buf*16384

  const int hi_b = (w < 2) ? 0 : 2;   // arrays: 0 Xhi, 1 Xlo, 2 Hhi, 3 Hlo
  const int dt = w & 1;
  const int ch0 = (w < 2) ? 0 : 3;

  // transposed-W per-(cl) base (unit = 512-element kc chunks)
  int wb[3];
#pragma unroll
  for (int cl = 0; cl < 3; ++cl)
    wb[cl] = (((ch0 + cl) * 5 + dblk) * 2 + dt) * 5;

  f32x4 acc[3][4];
#pragma unroll
  for (int a = 0; a < 3; ++a)
#pragma unroll
    for (int b = 0; b < 4; ++b) acc[a][b] = (f32x4){0.f, 0.f, 0.f, 0.f};

  auto loadH = [&](int kc, float* hv) {
    const int kb = kc * 32 + so * 8;
    const float* hrow = hcur + (size_t)gm * hstride + kb;
#pragma unroll
    for (int e = 0; e < 8; e += 2) {
      float x0 = 0.f, x1 = 0.f;
      if (rowok) {
        if (kb + e + 1 < HDIM) { float2 v2 = *(const float2*)(hrow + e); x0 = v2.x; x1 = v2.y; }
        else if (kb + e < HDIM) { x0 = hrow[e]; }
      }
      hv[e] = x0; hv[e + 1] = x1;
    }
  };
  auto writeH = [&](int buf, const float* hv) {
    bf16x8 vh, vl;
#pragma unroll
    for (int e = 0; e < 8; ++e) {
      ushort u = bf16_rne(hv[e]);
      vh[e] = (short)u;
      vl[e] = (short)bf16_rne(hv[e] - bf16f(u));
    }
    *(bf16x8*)((char*)smem + buf * 16384 + 2 * 4096 + lds_w_off) = vh;
    *(bf16x8*)((char*)smem + buf * 16384 + 3 * 4096 + lds_w_off) = vl;
  };
  auto loadB = [&](int kc, bf16x8* bh, bf16x8* bl) {
#pragma unroll
    for (int cl = 0; cl < 3; ++cl) {
      const int wo = ((wb[cl] + kc) << 9) + l * 8;
      bh[cl] = *(const bf16x8*)(Whi + wo);
      bl[cl] = *(const bf16x8*)(Wlo + wo);
    }
  };

  bf16x8 bhi[3], blo[3];
  loadB(0, bhi, blo);   // B(0) in flight under the staging + barrier

  {  // initial stage kc=0
    bf16x8 x0 = *(const bf16x8*)(Xhi + g_off);
    bf16x8 x1 = *(const bf16x8*)(Xlo + g_off);
    float hv[8];
    loadH(0, hv);
    *(bf16x8*)((char*)smem + 0 * 4096 + lds_w_off) = x0;
    *(bf16x8*)((char*)smem + 1 * 4096 + lds_w_off) = x1;
    writeH(0, hv);
  }
  __syncthreads();

#pragma unroll
  for (int kc = 0; kc < 5; ++kc) {
    const int cur = kc & 1;
    bf16x8 nX0, nX1;
    float nhv[8];
    bf16x8 nbh[3], nbl[3];
    if (kc < 4) {
      nX0 = *(const bf16x8*)(Xhi + g_off + (kc + 1) * 32);
      nX1 = *(const bf16x8*)(Xlo + g_off + (kc + 1) * 32);
      loadH(kc + 1, nhv);
      loadB(kc + 1, nbh, nbl);   // prefetch next-kc B: consumed next iteration
    }
    bf16x8 ahi[4], alo[4];
#pragma unroll
    for (int mt = 0; mt < 4; ++mt) {
      const int r = mt * 16 + c16;
      const int ob = (koct ^ ((r >> 1) & 3)) * 16;
      ahi[mt] = *(const bf16x8*)((char*)smem + cur * 16384 + hi_b * 4096 + r * 64 + ob);
      alo[mt] = *(const bf16x8*)((char*)smem + cur * 16384 + (hi_b + 1) * 4096 + r * 64 + ob);
    }
#pragma unroll
    for (int cl = 0; cl < 3; ++cl)
#pragma unroll
      for (int mt = 0; mt < 4; ++mt)
        acc[cl][mt] = __builtin_amdgcn_mfma_f32_16x16x32_bf16(ahi[mt], bhi[cl], acc[cl][mt], 0, 0, 0);
#pragma unroll
    for (int cl = 0; cl < 3; ++cl)
#pragma unroll
      for (int mt = 0; mt < 4; ++mt)
        acc[cl][mt] = __builtin_amdgcn_mfma_f32_16x16x32_bf16(ahi[mt], blo[cl], acc[cl][mt], 0, 0, 0);
#pragma unroll
    for (int cl = 0; cl < 3; ++cl)
#pragma unroll
      for (int mt = 0; mt < 4; ++mt)
        acc[cl][mt] = __builtin_amdgcn_mfma_f32_16x16x32_bf16(alo[mt], bhi[cl], acc[cl][mt], 0, 0, 0);
    if (kc < 4) {
      const int nb = cur ^ 1;
      *(bf16x8*)((char*)smem + nb * 16384 + 0 * 4096 + lds_w_off) = nX0;
      *(bf16x8*)((char*)smem + nb * 16384 + 1 * 4096 + lds_w_off) = nX1;
      writeH(nb, nhv);
#pragma unroll
      for (int cl = 0; cl < 3; ++cl) { bhi[cl] = nbh[cl]; blo[cl] = nbl[cl]; }
    }
    __syncthreads();
  }

  // epilogue: H-waves publish, X-waves combine + write hnext (stride 160)
  float* eps = (float*)smem;
  if (w >= 2) {
    const int wi = w - 2;
#pragma unroll
    for (int cl = 0; cl < 3; ++cl)
#pragma unroll
      for (int mt = 0; mt < 4; ++mt)
        *(f32x4*)&eps[(((wi * 3 + cl) * 4 + mt) * 64 + l) * 4] = acc[cl][mt];
  }
  __syncthreads();
  if (w < 2) {
    const int d = dblk * 32 + dt * 16 + c16;
    if (d < HDIM) {
      const float bir = bih[d], biz = bih[HDIM + d], bin = bih[2 * HDIM + d];
      const float bhr = bhh[d], bhz = bhh[HDIM + d], bhn = bhh[2 * HDIM + d];
#pragma unroll
      for (int mt = 0; mt < 4; ++mt) {
        const int mb = mblk * 64 + mt * 16 + koct * 4;
        f32x4 hr4 = *(const f32x4*)&eps[(((dt * 3 + 0) * 4 + mt) * 64 + l) * 4];
        f32x4 hz4 = *(const f32x4*)&eps[(((dt * 3 + 1) * 4 + mt) * 64 + l) * 4];
        f32x4 hn4 = *(const f32x4*)&eps[(((dt * 3 + 2) * 4 + mt) * 64 + l) * 4];
#pragma unroll
        for (int j = 0; j < 4; ++j) {
          const int m = mb + j;
          if (m < N_NODES) {
            const float r = 1.f / (1.f + __expf(-(acc[0][mt][j] + bir + hr4[j] + bhr)));
            const float z = 1.f / (1.f + __expf(-(acc[1][mt][j] + biz + hz4[j] + bhz)));
            const float na = acc[2][mt][j] + bin + r * (hn4[j] + bhn);
            const float nn = 1.f - 2.f / (__expf(2.f * na) + 1.f);  // tanh
            const float ho = hcur[(size_t)m * hstride + d];
            hnext[m * 160 + d] = (1.f - z) * nn + z * ho;
          }
        }
      }
    }
  }
}

// ---------------- readout ----------------
__global__ __launch_bounds__(64) void graph_accum_kernel(const float* __restrict__ h,
    const int* __restrict__ gids, float* __restrict__ gacc) {
  const int lane = threadIdx.x;
  const int nb = gridDim.x;
  int chunk = (N_NODES + nb - 1) / nb;
  int b = blockIdx.x * chunk, e = min(b + chunk, N_NODES);
  if (b >= e) return;
  float a0 = 0.f, a1 = 0.f, a2 = 0.f;
  int cur = gids[b];
  for (int i = b; i < e; ++i) {
    int gid = gids[i];
    if (gid != cur) {
      atomicAdd(&gacc[cur * HDIM + lane], a0);
      atomicAdd(&gacc[cur * HDIM + lane + 64], a1);
      if (lane < 22) atomicAdd(&gacc[cur * HDIM + lane + 128], a2);
      a0 = a1 = a2 = 0.f; cur = gid;
    }
    const float* hr = h + (size_t)i * 160;
    a0 += hr[lane]; a1 += hr[lane + 64];
    if (lane < 22) a2 += hr[lane + 128];
  }
  atomicAdd(&gacc[cur * HDIM + lane], a0);
  atomicAdd(&gacc[cur * HDIM + lane + 64], a1);
  if (lane < 22) atomicAdd(&gacc[cur * HDIM + lane + 128], a2);
}

__global__ __launch_bounds__(192) void readout_kernel(const float* __restrict__ gacc,
    const float* __restrict__ fc1w, const float* __restrict__ fc1b,
    const float* __restrict__ fc2w, const float* __restrict__ fc2b,
    const float* __restrict__ fclw, const float* __restrict__ fclb,
    float* __restrict__ out) {
  __shared__ float x0[HDIM];
  __shared__ float y1[80];
  __shared__ float y2[80];
  int g = blockIdx.x, t = threadIdx.x;
  if (t < HDIM) {
    float v = logf(gacc[g * HDIM + t]);
    if (v != v) v = 0.f;
    x0[t] = fmaxf(v, 0.f);
  }
  __syncthreads();
  if (t < 80) {
    float s = fc1b[t];
    for (int k = 0; k < HDIM; ++k) s += x0[k] * fc1w[t * HDIM + k];
    y1[t] = (s > 0.f) ? s : 0.01f * s;
  }
  __syncthreads();
  if (t < 80) {
    float s = fc2b[t];
    for (int k = 0; k < 80; ++k) s += y1[k] * fc2w[t * 80 + k];
    y2[t] = (s > 0.f) ? s : 0.01f * s;
  }
  __syncthreads();
  if (t < 10) {
    float s = fclb[t];
    for (int k = 0; k < 80; ++k) s += y2[k] * fclw[t * 80 + k];
    out[g * 10 + t] = s;
  }
}

// ---------------- launch ----------------
extern "C" void kernel_launch(void* const* d_in, const int* in_sizes, int n_in,
                              void* d_out, int out_size, void* d_ws, size_t ws_size,
                              hipStream_t stream) {
  const float* nodes = (const float*)d_in[0];
  const int* src = (const int*)d_in[1];
  const int* dst = (const int*)d_in[2];
  const int* gids = (const int*)d_in[3];
  const float* wih = (const float*)d_in[4];
  const float* whh = (const float*)d_in[5];
  const float* bih = (const float*)d_in[6];
  const float* bhh = (const float*)d_in[7];
  const float* fc1w = (const float*)d_in[8];
  const float* fc1b = (const float*)d_in[9];
  const float* fc2w = (const float*)d_in[10];
  const float* fc2b = (const float*)d_in[11];
  const float* fclw = (const float*)d_in[12];
  const float* fclb = (const float*)d_in[13];
  float* out = (float*)d_out;

  char* wsp = (char*)d_ws;
  size_t off = 0;
  auto carve = [&](size_t bytes) {
    void* p = wsp + off;
    off += (bytes + 255) & ~(size_t)255;
    return p;
  };
  int* counts   = (int*)carve((size_t)N_NODES * 4);
  int* rowstart = (int*)carve((size_t)(N_NODES + 1) * 4);
  int* cursor   = (int*)carve((size_t)N_NODES * 4);
  int* partials = (int*)carve((size_t)512 * 4);
  int* csr      = (int*)carve((size_t)N_EDGES * 4);
  ushort* Xhi   = (ushort*)carve((size_t)MROWS_PAD * 160 * 2);
  ushort* Xlo   = (ushort*)carve((size_t)MROWS_PAD * 160 * 2);
  float* hA     = (float*)carve((size_t)MROWS_PAD * 160 * 4);
  float* hB     = (float*)carve((size_t)MROWS_PAD * 160 * 4);
  ushort* Whi   = (ushort*)carve((size_t)153600 * 2);
  ushort* Wlo   = (ushort*)carve((size_t)153600 * 2);
  float* gacc   = (float*)carve((size_t)N_GRAPHS * HDIM * 4);
  (void)ws_size; (void)in_sizes; (void)n_in; (void)out_size;

  hipMemsetAsync(counts, 0, (size_t)N_NODES * 4, stream);
  hipMemsetAsync(gacc, 0, (size_t)N_GRAPHS * HDIM * 4, stream);

  hist_kernel<<<(N_EDGES + 255) / 256, 256, 0, stream>>>(dst, counts, N_EDGES);
  scan1_kernel<<<SCAN_NBLK, 256, 0, stream>>>(counts, partials);
  scan2_kernel<<<1, 512, 0, stream>>>(partials, rowstart);
  scan3_kernel<<<SCAN_NBLK, 256, 0, stream>>>(counts, partials, rowstart, cursor);
  fill_kernel<<<(N_EDGES + 255) / 256, 256, 0, stream>>>(src, dst, cursor, csr, N_EDGES);
  wbuild_kernel<<<600, 256, 0, stream>>>(wih, whh, Whi, Wlo);

  const float* hcur = nodes;
  int hstride = HDIM;
  float* hnxt = hA;
  for (int p = 0; p < PASSES; ++p) {
    segsum_kernel<<<25000, 256, 0, stream>>>(hcur, hstride, rowstart, csr, Xhi, Xlo);
    gru_mfma_kernel<<<7840, 256, 0, stream>>>(
        Xhi, Xlo, hcur, hstride, Whi, Wlo, bih, bhh, hnxt);
    hcur = hnxt;
    hstride = 160;
    hnxt = (hnxt == hA) ? hB : hA;
  }
  // final h in hcur (stride 160)

  graph_accum_kernel<<<512, 64, 0, stream>>>(hcur, gids, gacc);
  readout_kernel<<<N_GRAPHS, 192, 0, stream>>>(gacc, fc1w, fc1b, fc2w, fc2b, fclw, fclb, out);
}